// Round 11
// baseline (1295.744 us; speedup 1.0000x reference)
//
#include <hip/hip_runtime.h>

// Problem constants
constexpr int TT = 512;    // sequence length
constexpr int BB = 2048;   // batch
constexpr int HH = 11;     // hidden size
constexpr int GG = 44;     // 4*HH gates
constexpr int NL = 5;      // layers

typedef float v2f __attribute__((ext_vector_type(2)));

// quad_perm broadcast of lane q within each quad (ctrl = q * 0x55)
__device__ __forceinline__ float dpp_q0(float v) {
    return __int_as_float(__builtin_amdgcn_mov_dpp(__float_as_int(v), 0x00, 0xF, 0xF, false));
}
__device__ __forceinline__ float dpp_q1(float v) {
    return __int_as_float(__builtin_amdgcn_mov_dpp(__float_as_int(v), 0x55, 0xF, 0xF, false));
}
__device__ __forceinline__ float dpp_q3(float v) {
    return __int_as_float(__builtin_amdgcn_mov_dpp(__float_as_int(v), 0xFF, 0xF, 0xF, false));
}
// quad_perm [2,3,0,1]: lane q gets lane q^2 of its quad (ctrl 0x4E)
__device__ __forceinline__ float dpp_qswap2(float v) {
    return __int_as_float(__builtin_amdgcn_mov_dpp(__float_as_int(v), 0x4E, 0xF, 0xF, false));
}

// inp[b][t] = sum_k x[b][0][k][t]
__global__ void reduce_x(const float* __restrict__ x, float* __restrict__ inp) {
    int t = blockIdx.x * 256 + threadIdx.x;   // grid.x = 2 -> t in [0,512)
    int b = blockIdx.y;
    const float* p = x + (size_t)b * 32 * TT + t;
    float s = 0.f;
#pragma unroll
    for (int k = 0; k < 32; k++) s += p[k * TT];
    inp[(size_t)b * TT + t] = s;
}

// TWO sequences per wave: chain A = (b, d=0), chain B = (b, d=1).
// Two independent recurrences inside one in-order wave give ILP that
// fills each chain's serial-dependency stalls (measured: at 1 chain/wave,
// 4 waves/SIMD, VALUBusy plateaus at 74-77% -- exposed chain latency).
// Lane = 4*u + q (u hidden unit, q gate 0:i 1:f 2:g 3:o). Lanes u>=11
// carry zero weights (benign), stores masked.
//
// x staging: per-wave-private LDS, 4 buffers (A/B x double-buffer), no
// barriers. Chain B's staging write flips row order (wdwB) so both
// chains consume rows ascending. Next-chunk global loads issue at chunk
// start (vmcnt-covered by CH steps), ds_written at chunk end.
//
// h-dot: per-chain asm block (hardware-proven R9 pattern): 12 v_readlane
// -> s20..s31, then 6 v_pk_fma_f32 consuming SGPR pairs directly as the
// single scalar operand. Called once per chain; compiler interleaves the
// surrounding C++-level work of both chains.
//
// Scaled domain: weights/bias pre-multiplied by -log2e (i,f,o) or
// -2*log2e (g); c kept as c' = -2*log2e*c_true so both exp2 inputs need
// no per-step multiply.
template <int IND>
__global__ __launch_bounds__(256, 2)   // 2 waves/EU -> 256-VGPR budget
void lstm_layer(
    const float* __restrict__ xin,   // [chunk][TT][IND]
    float* __restrict__ out,         // [chunk][TT][22]
    const float* __restrict__ Wih,   // [2][GG][IND]
    const float* __restrict__ Whh,   // [2][GG][HH]
    const float* __restrict__ bih,   // [2][GG]
    const float* __restrict__ bhh)   // [2][GG]
{
    constexpr int NP    = (IND > 1) ? IND / 2 : 1;  // v2f pairs per x row
    constexpr int CH    = (IND == 1) ? 64 : 32;     // rows per staged chunk
    constexpr int NCH   = TT / CH;                  // chunks per sequence
    constexpr int NLD   = (CH * IND) / 64;          // dwords/lane per chunk
    constexpr int BUFSZ = CH * IND;

    __shared__ float smem[4 * 4 * BUFSZ];   // [wave][4 buffers]

    const float L2E   = 1.4426950408889634f;
    const float NL2E  = -L2E;
    const float N2L2E = -2.f * L2E;

    int tid  = threadIdx.x;
    int lane = tid & 63;
    int wid  = tid >> 6;
    int u = lane >> 2;
    int q = lane & 3;
    bool active = (u < HH);
    int grow = q * HH + u;

    int b = __builtin_amdgcn_readfirstlane((int)blockIdx.x * 4 + wid);

    float esc    = (q == 2) ? N2L2E : NL2E;
    float ascale = (q == 2) ? 2.f * N2L2E : 1.f;
    float aoff   = (q == 2) ? -N2L2E : 0.f;

    v2f   wihA[NP], wihB[NP];
    float wihA0 = 0.f, wihB0 = 0.f;
    v2f   whhA[6], whhB[6];
    v2f   biasA, biasB;
    if (active) {
        const float* wiA = Wih + (size_t)grow * IND;
        const float* wiB = Wih + (size_t)(GG + grow) * IND;
        if constexpr (IND == 1) {
            wihA0 = wiA[0] * esc;
            wihB0 = wiB[0] * esc;
        } else {
#pragma unroll
            for (int p = 0; p < NP; p++) wihA[p] = ((const v2f*)wiA)[p] * esc;
#pragma unroll
            for (int p = 0; p < NP; p++) wihB[p] = ((const v2f*)wiB)[p] * esc;
        }
        const float* whA = Whh + (size_t)grow * HH;
        const float* whB = Whh + (size_t)(GG + grow) * HH;
#pragma unroll
        for (int k = 0; k < 5; k++) {
            whhA[k] = (v2f){whA[2 * k] * esc, whA[2 * k + 1] * esc};
            whhB[k] = (v2f){whB[2 * k] * esc, whB[2 * k + 1] * esc};
        }
        whhA[5] = (v2f){whA[10] * esc, 0.f};
        whhB[5] = (v2f){whB[10] * esc, 0.f};
        biasA = (v2f){(bih[grow] + bhh[grow]) * esc, 0.f};
        biasB = (v2f){(bih[GG + grow] + bhh[GG + grow]) * esc, 0.f};
    } else {
        if constexpr (IND != 1) {
#pragma unroll
            for (int p = 0; p < NP; p++) { wihA[p] = (v2f){0.f, 0.f}; wihB[p] = (v2f){0.f, 0.f}; }
        }
#pragma unroll
        for (int k = 0; k < 6; k++) { whhA[k] = (v2f){0.f, 0.f}; whhB[k] = (v2f){0.f, 0.f}; }
        biasA = (v2f){0.f, 0.f};
        biasB = (v2f){0.f, 0.f};
    }

    float hA = 0.f, hB = 0.f;   // quad-uniform h of previous step
    float cA = 0.f, cB = 0.f;   // scaled domain c' = -2*log2e * c_true

    float* opA = out + (size_t)b * TT * 22 + u;                       // d=0
    float* opB = out + (size_t)b * TT * 22 + (size_t)(TT - 1) * 22 + HH + u; // d=1
    const bool doStore = (q == 0) && active;

    // ---- LDS buffers ----
    float* base = smem + wid * (4 * BUFSZ);
    float* xa0 = base;
    float* xa1 = base + BUFSZ;
    float* xb0 = base + 2 * BUFSZ;
    float* xb1 = base + 3 * BUFSZ;

    // ---- global staging ----
    const float* gA = xin + (size_t)b * TT * IND;                     // ascending
    const float* gB = xin + (size_t)b * TT * IND + (size_t)(TT - CH) * IND; // descending
    const int gstep = CH * IND;

    // chain B staging write map: flip row order so consumption ascends
    int wdwB[NLD];
#pragma unroll
    for (int k = 0; k < NLD; k++) {
        int p = k * 64 + lane;
        int row = p / IND;
        int col = p - row * IND;
        wdwB[k] = (CH - 1 - row) * IND + col;
    }

    {   // stage chunk 0, both chains
        float pA[NLD], pB[NLD];
#pragma unroll
        for (int k = 0; k < NLD; k++) pA[k] = gA[k * 64 + lane];
#pragma unroll
        for (int k = 0; k < NLD; k++) pB[k] = gB[k * 64 + lane];
#pragma unroll
        for (int k = 0; k < NLD; k++) xa0[k * 64 + lane] = pA[k];
#pragma unroll
        for (int k = 0; k < NLD; k++) xb0[wdwB[k]] = pB[k];
    }
    const float* gnA = gA + gstep;
    const float* gnB = gB - gstep;
    float* bufA = xa0;
    float* bufB = xb0;
    const float* lrA = bufA;
    const float* lrB = bufB;

    // row register ping-pong per chain (one row of lookahead over LDS)
    v2f   Xa0[NP], Xa1[NP], Xb0r[NP], Xb1r[NP];
    float Xa0s = 0.f, Xa1s = 0.f, Xb0rs = 0.f, Xb1rs = 0.f;

#define LOAD_ROW(DST, PTR)                                                    \
    do {                                                                      \
        if constexpr (IND == 1) {                                             \
            DST##s = (PTR)[0];                                                \
        } else {                                                              \
            _Pragma("unroll")                                                 \
            for (int p = 0; p < NP; p++) DST[p] = ((const v2f*)(PTR))[p];     \
        }                                                                     \
    } while (0)

    LOAD_ROW(Xa0, lrA);
    LOAD_ROW(Xb0r, lrB);

// R9-proven h-dot block: 12 readlane -> s20..s31, 6 pk_fma on SGPR pairs
#define HDOT_ASM(A0, A1, HV, W)                                               \
    asm volatile(                                                             \
        "v_readlane_b32 s20, %2, 0\n\t"                                       \
        "v_readlane_b32 s21, %2, 4\n\t"                                       \
        "v_readlane_b32 s22, %2, 8\n\t"                                       \
        "v_readlane_b32 s23, %2, 12\n\t"                                      \
        "v_readlane_b32 s24, %2, 16\n\t"                                      \
        "v_readlane_b32 s25, %2, 20\n\t"                                      \
        "v_readlane_b32 s26, %2, 24\n\t"                                      \
        "v_readlane_b32 s27, %2, 28\n\t"                                      \
        "v_readlane_b32 s28, %2, 32\n\t"                                      \
        "v_readlane_b32 s29, %2, 36\n\t"                                      \
        "v_readlane_b32 s30, %2, 40\n\t"                                      \
        "v_readlane_b32 s31, %2, 44\n\t"                                      \
        "v_pk_fma_f32 %0, s[20:21], %3, %0\n\t"                               \
        "v_pk_fma_f32 %1, s[22:23], %4, %1\n\t"                               \
        "v_pk_fma_f32 %0, s[24:25], %5, %0\n\t"                               \
        "v_pk_fma_f32 %1, s[26:27], %6, %1\n\t"                               \
        "v_pk_fma_f32 %0, s[28:29], %7, %0\n\t"                               \
        "v_pk_fma_f32 %1, s[30:31], %8, %1"                                   \
        : "+v"(A0), "+v"(A1)                                                  \
        : "v"(HV), "v"(W[0]), "v"(W[1]), "v"(W[2]),                           \
          "v"(W[3]), "v"(W[4]), "v"(W[5])                                     \
        : "s20","s21","s22","s23","s24","s25","s26","s27",                    \
          "s28","s29","s30","s31")

#define LSTM_STEP2(CA, NA, CB, NB, DOPF)                                      \
    do {                                                                      \
        v2f aA0, aA1, aB0, aB1;                                               \
        if constexpr (IND == 1) {                                             \
            aA0 = biasA; aA1 = (v2f){0.f, 0.f};                               \
            aB0 = biasB; aB1 = (v2f){0.f, 0.f};                               \
        } else {                                                              \
            aA0 = __builtin_elementwise_fma(CA[0], wihA[0], biasA);           \
            aA1 = CA[1] * wihA[1];                                            \
            aB0 = __builtin_elementwise_fma(CB[0], wihB[0], biasB);           \
            aB1 = CB[1] * wihB[1];                                            \
            _Pragma("unroll")                                                 \
            for (int p = 2; p < NP; p++) {                                    \
                if (p & 1) { aA1 = __builtin_elementwise_fma(CA[p], wihA[p], aA1); \
                             aB1 = __builtin_elementwise_fma(CB[p], wihB[p], aB1); } \
                else       { aA0 = __builtin_elementwise_fma(CA[p], wihA[p], aA0); \
                             aB0 = __builtin_elementwise_fma(CB[p], wihB[p], aB0); } \
            }                                                                 \
        }                                                                     \
        if (DOPF) {                                                           \
            lrA += IND; LOAD_ROW(NA, lrA);                                    \
            lrB += IND; LOAD_ROW(NB, lrB);                                    \
        }                                                                     \
        HDOT_ASM(aA0, aA1, hA, whhA);                                         \
        HDOT_ASM(aB0, aB1, hB, whhB);                                         \
        v2f sA = aA0 + aA1;                                                   \
        v2f sB = aB0 + aB1;                                                   \
        float preA = sA.x + sA.y;                                             \
        float preB = sB.x + sB.y;                                             \
        if constexpr (IND == 1) {                                             \
            preA = fmaf(CA##s, wihA0, preA);                                  \
            preB = fmaf(CB##s, wihB0, preB);                                  \
        }                                                                     \
        float eA   = __builtin_amdgcn_exp2f(preA);                            \
        float eB   = __builtin_amdgcn_exp2f(preB);                            \
        float actA = fmaf(ascale, __builtin_amdgcn_rcpf(1.f + eA), aoff);     \
        float actB = fmaf(ascale, __builtin_amdgcn_rcpf(1.f + eB), aoff);     \
        float igA  = actA * dpp_qswap2(actA);                                 \
        float igB  = actB * dpp_qswap2(actB);                                 \
        float igbA = dpp_q0(igA);                                             \
        float igbB = dpp_q0(igB);                                             \
        float fvA  = dpp_q1(actA);                                            \
        float fvB  = dpp_q1(actB);                                            \
        float ovA  = dpp_q3(actA);                                            \
        float ovB  = dpp_q3(actB);                                            \
        cA = fmaf(fvA, cA, igbA);                                             \
        cB = fmaf(fvB, cB, igbB);                                             \
        float e2A = __builtin_amdgcn_exp2f(cA);                               \
        float e2B = __builtin_amdgcn_exp2f(cB);                               \
        float thA = fmaf(2.f, __builtin_amdgcn_rcpf(1.f + e2A), -1.f);        \
        float thB = fmaf(2.f, __builtin_amdgcn_rcpf(1.f + e2B), -1.f);        \
        float hA_ = ovA * thA;                                                \
        float hB_ = ovB * thB;                                                \
        if (doStore) { *opA = hA_; *opB = hB_; }                              \
        opA += 22;                                                            \
        opB -= 22;                                                            \
        hA = hA_;                                                             \
        hB = hB_;                                                             \
    } while (0)

    for (int ch = 0; ch < NCH; ch++) {
        const bool last = (ch + 1 == NCH);
        float pfA[NLD], pfB[NLD];
        if (!last) {   // issue next-chunk loads; vmcnt-covered by CH steps
#pragma unroll
            for (int k = 0; k < NLD; k++) pfA[k] = gnA[k * 64 + lane];
#pragma unroll
            for (int k = 0; k < NLD; k++) pfB[k] = gnB[k * 64 + lane];
        }
        for (int sl = 0; sl < CH - 2; sl += 2) {
            LSTM_STEP2(Xa0, Xa1, Xb0r, Xb1r, true);
            LSTM_STEP2(Xa1, Xa0, Xb1r, Xb0r, true);
        }
        LSTM_STEP2(Xa0, Xa1, Xb0r, Xb1r, true);    // step CH-2
        LSTM_STEP2(Xa1, Xa0, Xb1r, Xb0r, false);   // step CH-1
        if (!last) {
            float* nbA = (bufA == xa0) ? xa1 : xa0;
            float* nbB = (bufB == xb0) ? xb1 : xb0;
#pragma unroll
            for (int k = 0; k < NLD; k++) nbA[k * 64 + lane] = pfA[k];
#pragma unroll
            for (int k = 0; k < NLD; k++) nbB[wdwB[k]] = pfB[k];
            bufA = nbA; bufB = nbB;
            lrA = bufA; lrB = bufB;
            LOAD_ROW(Xa0, lrA);
            LOAD_ROW(Xb0r, lrB);
            gnA += gstep;
            gnB -= gstep;
        }
    }
#undef LSTM_STEP2
#undef HDOT_ASM
#undef LOAD_ROW
}

extern "C" void kernel_launch(void* const* d_in, const int* in_sizes, int n_in,
                              void* d_out, int out_size, void* d_ws, size_t ws_size,
                              hipStream_t stream) {
    const float* x        = (const float*)d_in[0]; // [2048,1,32,512]
    const float* W_ih0    = (const float*)d_in[1]; // [2,44,1]
    const float* W_ih_rest= (const float*)d_in[2]; // [4,2,44,22]
    const float* W_hh     = (const float*)d_in[3]; // [5,2,44,11]
    const float* b_ih     = (const float*)d_in[4]; // [5,2,44]
    const float* b_hh     = (const float*)d_in[5]; // [5,2,44]
    float* out = (float*)d_out;                    // [2048,512,22]

    // Workspace: one ping buffer of chunk*TT*22 floats; largest pow2 chunk
    // that fits ws_size. The x-reduction is staged in the same buffer (its
    // lifetime ends when layer 1 overwrites it). d_out is the pong buffer.
    const size_t perB = (size_t)TT * 22 * sizeof(float);
    int chunk = BB;
    while (chunk > 4 && (size_t)chunk * perB > ws_size) chunk >>= 1;
    float* wsbuf = (float*)d_ws;

    for (int c0 = 0; c0 < BB; c0 += chunk) {
        const float* xc   = x + (size_t)c0 * 32 * TT;
        float*       outc = out + (size_t)c0 * TT * 22;
        const int nblk = chunk / 4;  // 4 waves/block, 2 sequences per wave

        reduce_x<<<dim3(2, chunk), 256, 0, stream>>>(xc, wsbuf);

        lstm_layer<1><<<nblk, 256, 0, stream>>>(wsbuf, outc, W_ih0, W_hh, b_ih, b_hh);

        for (int l = 1; l < NL; l++) {
            const float* src = (l & 1) ? outc : wsbuf;
            float*       dst = (l & 1) ? wsbuf : outc;
            lstm_layer<22><<<nblk, 256, 0, stream>>>(
                src, dst,
                W_ih_rest + (size_t)(l - 1) * 2 * GG * 22,
                W_hh + (size_t)l * 2 * GG * HH,
                b_ih + (size_t)l * 2 * GG,
                b_hh + (size_t)l * 2 * GG);
        }
    }
}